// Round 17
// baseline (232.540 us; speedup 1.0000x reference)
//
#include <hip/hip_runtime.h>

// LightGCN 3-hop propagation, D=64, bf16 features / fp32 accumulate.
// R16: R15 post-mortem — 8-chain / 16-chain / dual-row all converge at
// 42us (VGPR 16: compiler serializes batches). New spmm: 4 edges per
// gather INSTRUCTION. Lane L=(grp=L>>4, sub=L&15); one dwordx2 load makes
// lane L read dims [4sub..4sub+3] of edge (4g+grp) -> 4 edges/instruction,
// same bytes. 4 static acc chains; row-end shfl_xor(16,32) butterfly; lanes
// 0-15 store 128B. Tail masking FREE: masked slots use col=c0 (same line,
// no extra fetch), val=0 — unlike R13's cross-row masking.

#define NBUCKET 3125     // N=100000 rows, 32 per bucket
#define BSHIFT  5
#define BMASK   31
#define NCHUNK  256      // edge chunks; E=1.6M -> 6250 edges/chunk

static __device__ __forceinline__ ushort f2bf(float f) {
    unsigned u = __float_as_uint(f);
    unsigned r = (u + 0x7fffu + ((u >> 16) & 1u)) >> 16;   // RNE
    return (ushort)r;
}
static __device__ __forceinline__ float bf2f(ushort b) {
    return __uint_as_float(((unsigned)b) << 16);
}
static __device__ __forceinline__ float bflo(unsigned w) {   // low bf16 of dword
    return __uint_as_float(w << 16);
}
static __device__ __forceinline__ float bfhi(unsigned w) {   // high bf16 of dword
    return __uint_as_float(w & 0xFFFF0000u);
}

__global__ __launch_bounds__(256) void f2bf_k(
    const float* __restrict__ in, ushort* __restrict__ out, int n4)
{
    int i = blockIdx.x * blockDim.x + threadIdx.x;
    if (i >= n4) return;
    float4 v = *(const float4*)(in + (long)i * 4);
    ushort4 o;
    o.x = f2bf(v.x); o.y = f2bf(v.y); o.z = f2bf(v.z); o.w = f2bf(v.w);
    *(ushort4*)(out + (long)i * 4) = o;
}

// pass A: per-chunk bucket histogram in LDS (no global atomics); 16 waves
__global__ __launch_bounds__(1024) void count_k(
    const int* __restrict__ rows, int* __restrict__ cnt, int E, int chunkE)
{
    __shared__ unsigned h[NBUCKET];
    int c = blockIdx.x;
    for (int b = threadIdx.x; b < NBUCKET; b += 1024) h[b] = 0u;
    __syncthreads();
    int s = c * chunkE;
    int e = min(s + chunkE, E);
    for (int j = s + (int)threadIdx.x; j < e; j += 1024)
        atomicAdd(&h[rows[j] >> BSHIFT], 1u);
    __syncthreads();
    int* o = cnt + (long)c * NBUCKET;
    for (int b = threadIdx.x; b < NBUCKET; b += 1024) o[b] = (int)h[b];
}

// pass B: per-bucket local exclusive prefix over chunks + bucket totals.
__global__ __launch_bounds__(256) void localscan_k(
    const int* __restrict__ cnt, int* __restrict__ offs,
    int* __restrict__ totals)
{
    int b = blockIdx.x * 256 + threadIdx.x;
    if (b >= NBUCKET) return;
    int run = 0;
    #pragma unroll 8
    for (int c = 0; c < NCHUNK; ++c) {
        long i = (long)c * NBUCKET + b;
        int v = cnt[i];
        offs[i] = run;
        run += v;
    }
    totals[b] = run;
}

// fused exclusive scan over nbucket elements; single block of 1024
__global__ __launch_bounds__(1024) void scan_fused_k(
    const int* __restrict__ totals, int* __restrict__ bucket_start, int nbucket)
{
    __shared__ int sm[1024];
    __shared__ int carry_s;
    if (threadIdx.x == 0) carry_s = 0;
    __syncthreads();
    int ntile = (nbucket + 1023) / 1024;
    for (int t = 0; t < ntile; ++t) {
        int i = t * 1024 + threadIdx.x;
        int v = (i < nbucket) ? totals[i] : 0;
        sm[threadIdx.x] = v;
        __syncthreads();
        for (int off = 1; off < 1024; off <<= 1) {
            int add = (threadIdx.x >= off) ? sm[threadIdx.x - off] : 0;
            __syncthreads();
            sm[threadIdx.x] += add;
            __syncthreads();
        }
        int c0 = carry_s;
        if (i < nbucket) bucket_start[i] = c0 + sm[threadIdx.x] - v;
        __syncthreads();
        if (threadIdx.x == 1023) carry_s = c0 + sm[1023];
        __syncthreads();
    }
    if (threadIdx.x == 0) bucket_start[nbucket] = carry_s;   // == E
}

// pass C: partition edges into bucket segments; LDS cursors only; 16 waves.
// edge payload: .x = (row&31)<<17 | col  (col < 2^17), .y = val bits
__global__ __launch_bounds__(1024) void scatter3_k(
    const int* __restrict__ rows, const int* __restrict__ cols,
    const float* __restrict__ vals, const int* __restrict__ offs,
    const int* __restrict__ bucket_start,
    int2* __restrict__ edges, int E, int chunkE)
{
    __shared__ int cur[NBUCKET];
    int c = blockIdx.x;
    const int* o = offs + (long)c * NBUCKET;
    for (int b = threadIdx.x; b < NBUCKET; b += 1024)
        cur[b] = o[b] + bucket_start[b];
    __syncthreads();
    int s = c * chunkE;
    int e = min(s + chunkE, E);
    for (int j = s + (int)threadIdx.x; j < e; j += 1024) {
        int r = rows[j];
        int pos = atomicAdd(&cur[r >> BSHIFT], 1);
        edges[pos] = make_int2(((r & BMASK) << 17) | cols[j],
                               __float_as_int(vals[j]));
    }
}

// pass D: per-bucket counting sort, one 256-thread block per bucket.
// Writes a 16-entry zero pad after the last bucket (spmm 16-edge over-read).
__global__ __launch_bounds__(256) void sort_bkt_k(
    const int* __restrict__ bucket_start, const int2* __restrict__ edges_in,
    int2* __restrict__ edges_out, int* __restrict__ row_start, int nbucket)
{
    __shared__ int cnt_s[32];
    __shared__ int cur_s[32];
    int bk = blockIdx.x;
    int t = (int)threadIdx.x;
    int s = bucket_start[bk];
    int e = bucket_start[bk + 1];
    if (t < 32) cnt_s[t] = 0;
    __syncthreads();
    for (int j = s + t; j < e; j += 256)
        atomicAdd(&cnt_s[(unsigned)edges_in[j].x >> 17], 1);
    __syncthreads();
    if (t == 0) {
        int run = s;
        #pragma unroll
        for (int r = 0; r < 32; ++r) {
            int c = cnt_s[r];
            cur_s[r] = run;
            row_start[bk * 32 + r] = run;
            run += c;
        }
    }
    __syncthreads();
    for (int j = s + t; j < e; j += 256) {
        int2 ed = edges_in[j];
        int pos = atomicAdd(&cur_s[(unsigned)ed.x >> 17], 1);
        edges_out[pos] = ed;
    }
    if (bk == nbucket - 1) {
        if (t == 0) row_start[nbucket * 32] = e;      // == E
        if (t < 16) edges_out[e + t] = make_int2(0, 0);  // zero-val pad
    }
}

// spmm: one wave per row. lane = (grp = L>>4, sub = L&15); one dwordx2
// gather per 4 edges (lane L reads dims [4sub..4sub+3] of edge 4g+grp).
// 4 static acc chains; butterfly reduce over grp; lanes 0-15 store 128B.
// Masked tail slots: col = c0 (same line, free), val = 0.
__global__ __launch_bounds__(256) void spmm_csr_k(
    const int* __restrict__ row_start, const int2* __restrict__ edges,
    const ushort* __restrict__ x, ushort* __restrict__ y, int N)
{
    int wid = __builtin_amdgcn_readfirstlane((int)(threadIdx.x >> 6));
    int r = blockIdx.x * 4 + wid;
    if (r >= N) return;
    int lane = (int)(threadIdx.x & 63);
    int grp = lane >> 4;
    int sub = lane & 15;
    int s = row_start[r];      // wave-uniform -> s_load
    int e = row_start[r + 1];
    const uint2* xv = (const uint2*)x;   // row = 16 uint2 (128B)

    float a00=0.f,a01=0.f,a02=0.f,a03=0.f;   // chain per gather-slot g
    float a10=0.f,a11=0.f,a12=0.f,a13=0.f;
    float a20=0.f,a21=0.f,a22=0.f,a23=0.f;
    float a30=0.f,a31=0.f,a32=0.f,a33=0.f;

    for (int j = s; j < e; j += 16) {
        // 16 scalar edge loads (may over-read into next rows / global pad)
        int2 E0  = edges[j];      int2 E1  = edges[j + 1];
        int2 E2  = edges[j + 2];  int2 E3  = edges[j + 3];
        int2 E4  = edges[j + 4];  int2 E5  = edges[j + 5];
        int2 E6  = edges[j + 6];  int2 E7  = edges[j + 7];
        int2 E8  = edges[j + 8];  int2 E9  = edges[j + 9];
        int2 E10 = edges[j + 10]; int2 E11 = edges[j + 11];
        int2 E12 = edges[j + 12]; int2 E13 = edges[j + 13];
        int2 E14 = edges[j + 14]; int2 E15 = edges[j + 15];
        int c0 = E0.x & 0x1FFFF;
        // masked col/val per slot (scalar cselect; masked col = c0 -> same line)
        #define CS(i, Ei) \
            int  c##i = (j + i < e) ? (Ei.x & 0x1FFFF) : c0; \
            float v##i = (j + i < e) ? __int_as_float(Ei.y) : 0.f
        int cc0 = c0; float v0 = (j < e) ? __int_as_float(E0.y) : 0.f; (void)cc0;
        CS(1, E1);  CS(2, E2);  CS(3, E3);
        CS(4, E4);  CS(5, E5);  CS(6, E6);  CS(7, E7);
        CS(8, E8);  CS(9, E9);  CS(10, E10); CS(11, E11);
        CS(12, E12); CS(13, E13); CS(14, E14); CS(15, E15);
        #undef CS
        // per-gather lane select of (col, val) by grp, then dwordx2 gather
        #define G4(gi, ca, cb, cc, cd, va, vb, vc, vd, A0, A1, A2, A3) { \
            int   cg = (grp < 2) ? ((grp & 1) ? cb : ca) : ((grp & 1) ? cd : cc); \
            float vg = (grp < 2) ? ((grp & 1) ? vb : va) : ((grp & 1) ? vd : vc); \
            uint2 g = xv[(long)cg * 16 + sub]; \
            A0 += vg * bflo(g.x); A1 += vg * bfhi(g.x); \
            A2 += vg * bflo(g.y); A3 += vg * bfhi(g.y); }
        G4(0, c0, c1, c2, c3, v0, v1, v2, v3, a00, a01, a02, a03);
        G4(1, c4, c5, c6, c7, v4, v5, v6, v7, a10, a11, a12, a13);
        G4(2, c8, c9, c10, c11, v8, v9, v10, v11, a20, a21, a22, a23);
        G4(3, c12, c13, c14, c15, v12, v13, v14, v15, a30, a31, a32, a33);
        #undef G4
    }
    // merge the 4 chains, then butterfly over grp (lanes sub, sub+16, +32, +48)
    float k0 = (a00 + a10) + (a20 + a30);
    float k1 = (a01 + a11) + (a21 + a31);
    float k2 = (a02 + a12) + (a22 + a32);
    float k3 = (a03 + a13) + (a23 + a33);
    k0 += __shfl_xor(k0, 16, 64); k0 += __shfl_xor(k0, 32, 64);
    k1 += __shfl_xor(k1, 16, 64); k1 += __shfl_xor(k1, 32, 64);
    k2 += __shfl_xor(k2, 16, 64); k2 += __shfl_xor(k2, 32, 64);
    k3 += __shfl_xor(k3, 16, 64); k3 += __shfl_xor(k3, 32, 64);
    if (lane < 16) {
        uint2 o;
        o.x = (unsigned)f2bf(k0) | ((unsigned)f2bf(k1) << 16);
        o.y = (unsigned)f2bf(k2) | ((unsigned)f2bf(k3) << 16);
        ((uint2*)y)[(long)r * 16 + sub] = o;   // 16 lanes x 8B = 128B
    }
}

// out[0..2] = 0.25*emb[idx] (hop-0 term), out[3..5] = emb[idx]; float4 lanes
__global__ __launch_bounds__(256) void init_out_k(
    const float* __restrict__ emb, const int* __restrict__ n0,
    const int* __restrict__ n1, const int* __restrict__ n2,
    float* __restrict__ out, int B)
{
    int tid = blockIdx.x * blockDim.x + threadIdx.x;
    int total = 3 * B * 16;                 // float4 granularity
    if (tid >= total) return;
    int arr = tid / (B * 16);
    int rem = tid - arr * (B * 16);
    int b = rem >> 4;
    int d4 = rem & 15;
    const int* __restrict__ idx = (arr == 0) ? n0 : ((arr == 1) ? n1 : n2);
    float4 v = *(const float4*)(emb + (long)idx[b] * 64 + d4 * 4);
    float4 q = make_float4(0.25f * v.x, 0.25f * v.y, 0.25f * v.z, 0.25f * v.w);
    *(float4*)(out + (long)arr * B * 64 + (long)rem * 4) = q;
    *(float4*)(out + (long)(arr + 3) * B * 64 + (long)rem * 4) = v;
}

// pooled += 0.25 * agg_bf16[idx]
__global__ __launch_bounds__(256) void gather_add_k(
    const ushort* __restrict__ agg, const int* __restrict__ n0,
    const int* __restrict__ n1, const int* __restrict__ n2,
    float* __restrict__ out, int B)
{
    int tid = blockIdx.x * blockDim.x + threadIdx.x;
    int total = 3 * B * 16;
    if (tid >= total) return;
    int arr = tid / (B * 16);
    int rem = tid - arr * (B * 16);
    int b = rem >> 4;
    int d4 = rem & 15;
    const int* __restrict__ idx = (arr == 0) ? n0 : ((arr == 1) ? n1 : n2);
    ushort4 v = *(const ushort4*)(agg + (long)idx[b] * 64 + d4 * 4);
    float* o = out + (long)arr * B * 64 + (long)rem * 4;
    float4 cur = *(float4*)o;
    cur.x += 0.25f * bf2f(v.x); cur.y += 0.25f * bf2f(v.y);
    cur.z += 0.25f * bf2f(v.z); cur.w += 0.25f * bf2f(v.w);
    *(float4*)o = cur;
}

extern "C" void kernel_launch(void* const* d_in, const int* in_sizes, int n_in,
                              void* d_out, int out_size, void* d_ws, size_t ws_size,
                              hipStream_t stream)
{
    const float* emb  = (const float*)d_in[0];
    const int*   rows = (const int*)d_in[1];
    const int*   cols = (const int*)d_in[2];
    const float* vals = (const float*)d_in[3];
    const int*   node = (const int*)d_in[4];
    const int*   pos  = (const int*)d_in[5];
    const int*   neg  = (const int*)d_in[6];
    float* out = (float*)d_out;

    const int E = in_sizes[1];
    const int B = in_sizes[4];
    const int N = in_sizes[0] / 64;
    const size_t nd = (size_t)N * 64;
    const int chunkE = (E + NCHUNK - 1) / NCHUNK;
    const int nbucket = (N + BMASK) >> BSHIFT;     // 3125 for N=100000

    // workspace layout
    ushort* aggA        = (ushort*)d_ws;            // N*64 bf16
    ushort* aggB        = aggA + nd;                // N*64 bf16 (also emb cast)
    int2*  edges        = (int2*)(aggB + nd);       // E (bucket-grouped)
    int2*  edges2       = edges + E;                // E + 16 (row-sorted + pad)
    int*   cnt          = (int*)(edges2 + E + 16);  // NCHUNK * NBUCKET
    int*   totals       = cnt + (long)NCHUNK * NBUCKET;  // NBUCKET
    int*   bucket_start = totals + NBUCKET;         // NBUCKET+1
    int*   row_start    = bucket_start + NBUCKET + 1;    // nbucket*32+1
    // offs reuses edges2's storage (dead before sort_bkt writes edges2)
    int*   offs         = (int*)edges2;             // NCHUNK * NBUCKET

    const int gtotal   = 3 * B * 16;
    const int gblocks  = (gtotal + 255) / 256;
    const int cblocks  = ((int)(nd / 4) + 255) / 256;
    const int bblocks  = (nbucket + 255) / 256;     // 13
    const int rblocks  = (N + 3) / 4;               // spmm: 4 rows/block

    init_out_k<<<gblocks, 256, 0, stream>>>(emb, node, pos, neg, out, B);
    f2bf_k<<<cblocks, 256, 0, stream>>>(emb, aggB, (int)(nd / 4));

    // ---- bucketed partition + per-bucket counting sort; no global atomics ----
    count_k<<<NCHUNK, 1024, 0, stream>>>(rows, cnt, E, chunkE);
    localscan_k<<<bblocks, 256, 0, stream>>>(cnt, offs, totals);
    scan_fused_k<<<1, 1024, 0, stream>>>(totals, bucket_start, nbucket);
    scatter3_k<<<NCHUNK, 1024, 0, stream>>>(rows, cols, vals, offs, bucket_start, edges, E, chunkE);
    sort_bkt_k<<<nbucket, 256, 0, stream>>>(bucket_start, edges, edges2, row_start, nbucket);

    // ---- 3 propagation hops, 4-edges-per-gather spmm ----
    spmm_csr_k<<<rblocks, 256, 0, stream>>>(row_start, edges2, aggB, aggA, N);
    gather_add_k<<<gblocks, 256, 0, stream>>>(aggA, node, pos, neg, out, B);

    spmm_csr_k<<<rblocks, 256, 0, stream>>>(row_start, edges2, aggA, aggB, N);
    gather_add_k<<<gblocks, 256, 0, stream>>>(aggB, node, pos, neg, out, B);

    spmm_csr_k<<<rblocks, 256, 0, stream>>>(row_start, edges2, aggB, aggA, N);
    gather_add_k<<<gblocks, 256, 0, stream>>>(aggA, node, pos, neg, out, B);
}

// Round 18
// 197.413 us; speedup vs baseline: 1.1779x; 1.1779x over previous
//
#include <hip/hip_runtime.h>

// LightGCN 3-hop propagation, D=64, bf16 features / fp32 accumulate.
// R18: revert to the R11 best-known config (203.7us). R15 dual-row (+7us)
// and R16 packed-gather (VALU-bound, +10us/spmm) both regressed; four spmm
// structures converge at ~42us with ~90MB L2-miss traffic at 2.1-2.5 TB/s
// -> fabric/L3 random-line ceiling. This is R11 exactly, plus a 2-edge
// cascade step in the spmm tail (saves one round-trip when deg%4==3).

#define NBUCKET 3125     // N=100000 rows, 32 per bucket
#define BSHIFT  5
#define BMASK   31
#define NCHUNK  256      // edge chunks; E=1.6M -> 6250 edges/chunk

static __device__ __forceinline__ ushort f2bf(float f) {
    unsigned u = __float_as_uint(f);
    unsigned r = (u + 0x7fffu + ((u >> 16) & 1u)) >> 16;   // RNE
    return (ushort)r;
}
static __device__ __forceinline__ float bf2f(ushort b) {
    return __uint_as_float(((unsigned)b) << 16);
}

__global__ __launch_bounds__(256) void f2bf_k(
    const float* __restrict__ in, ushort* __restrict__ out, int n4)
{
    int i = blockIdx.x * blockDim.x + threadIdx.x;
    if (i >= n4) return;
    float4 v = *(const float4*)(in + (long)i * 4);
    ushort4 o;
    o.x = f2bf(v.x); o.y = f2bf(v.y); o.z = f2bf(v.z); o.w = f2bf(v.w);
    *(ushort4*)(out + (long)i * 4) = o;
}

// pass A: per-chunk bucket histogram in LDS (no global atomics); 16 waves
__global__ __launch_bounds__(1024) void count_k(
    const int* __restrict__ rows, int* __restrict__ cnt, int E, int chunkE)
{
    __shared__ unsigned h[NBUCKET];
    int c = blockIdx.x;
    for (int b = threadIdx.x; b < NBUCKET; b += 1024) h[b] = 0u;
    __syncthreads();
    int s = c * chunkE;
    int e = min(s + chunkE, E);
    for (int j = s + (int)threadIdx.x; j < e; j += 1024)
        atomicAdd(&h[rows[j] >> BSHIFT], 1u);
    __syncthreads();
    int* o = cnt + (long)c * NBUCKET;
    for (int b = threadIdx.x; b < NBUCKET; b += 1024) o[b] = (int)h[b];
}

// pass B: per-bucket local exclusive prefix over chunks + bucket totals.
__global__ __launch_bounds__(256) void localscan_k(
    const int* __restrict__ cnt, int* __restrict__ offs,
    int* __restrict__ totals)
{
    int b = blockIdx.x * 256 + threadIdx.x;
    if (b >= NBUCKET) return;
    int run = 0;
    #pragma unroll 8
    for (int c = 0; c < NCHUNK; ++c) {
        long i = (long)c * NBUCKET + b;
        int v = cnt[i];
        offs[i] = run;
        run += v;
    }
    totals[b] = run;
}

// fused exclusive scan over nbucket elements; single block of 1024
__global__ __launch_bounds__(1024) void scan_fused_k(
    const int* __restrict__ totals, int* __restrict__ bucket_start, int nbucket)
{
    __shared__ int sm[1024];
    __shared__ int carry_s;
    if (threadIdx.x == 0) carry_s = 0;
    __syncthreads();
    int ntile = (nbucket + 1023) / 1024;
    for (int t = 0; t < ntile; ++t) {
        int i = t * 1024 + threadIdx.x;
        int v = (i < nbucket) ? totals[i] : 0;
        sm[threadIdx.x] = v;
        __syncthreads();
        for (int off = 1; off < 1024; off <<= 1) {
            int add = (threadIdx.x >= off) ? sm[threadIdx.x - off] : 0;
            __syncthreads();
            sm[threadIdx.x] += add;
            __syncthreads();
        }
        int c0 = carry_s;
        if (i < nbucket) bucket_start[i] = c0 + sm[threadIdx.x] - v;
        __syncthreads();
        if (threadIdx.x == 1023) carry_s = c0 + sm[1023];
        __syncthreads();
    }
    if (threadIdx.x == 0) bucket_start[nbucket] = carry_s;   // == E
}

// pass C: partition edges into bucket segments; LDS cursors only; 16 waves.
// edge payload: .x = (row&31)<<17 | col  (col < 2^17), .y = val bits
__global__ __launch_bounds__(1024) void scatter3_k(
    const int* __restrict__ rows, const int* __restrict__ cols,
    const float* __restrict__ vals, const int* __restrict__ offs,
    const int* __restrict__ bucket_start,
    int2* __restrict__ edges, int E, int chunkE)
{
    __shared__ int cur[NBUCKET];
    int c = blockIdx.x;
    const int* o = offs + (long)c * NBUCKET;
    for (int b = threadIdx.x; b < NBUCKET; b += 1024)
        cur[b] = o[b] + bucket_start[b];
    __syncthreads();
    int s = c * chunkE;
    int e = min(s + chunkE, E);
    for (int j = s + (int)threadIdx.x; j < e; j += 1024) {
        int r = rows[j];
        int pos = atomicAdd(&cur[r >> BSHIFT], 1);
        edges[pos] = make_int2(((r & BMASK) << 17) | cols[j],
                               __float_as_int(vals[j]));
    }
}

// pass D: per-bucket LDS counting sort over the 32 row-locals.
// One wave per bucket; intra-wave program order -> no barriers needed.
__global__ __launch_bounds__(256) void sort_bkt_k(
    const int* __restrict__ bucket_start, const int2* __restrict__ edges_in,
    int2* __restrict__ edges_out, int* __restrict__ row_start, int nbucket)
{
    __shared__ int cur[4][32];
    int w = (int)(threadIdx.x >> 6);
    int lane = (int)(threadIdx.x & 63);
    int bk = blockIdx.x * 4 + w;
    if (bk >= nbucket) return;
    int s = bucket_start[bk];
    int e = bucket_start[bk + 1];
    if (lane < 32) cur[w][lane] = 0;
    for (int j = s + lane; j < e; j += 64)
        atomicAdd(&cur[w][(unsigned)edges_in[j].x >> 17], 1);
    if (lane == 0) {
        int run = s;
        #pragma unroll
        for (int r = 0; r < 32; ++r) {
            int c = cur[w][r];
            cur[w][r] = run;
            row_start[bk * 32 + r] = run;
            run += c;
        }
    }
    for (int j = s + lane; j < e; j += 64) {
        int2 ed = edges_in[j];
        int pos = atomicAdd(&cur[w][(unsigned)ed.x >> 17], 1);
        edges_out[pos] = ed;
    }
    if (bk == nbucket - 1 && lane == 0) row_start[nbucket * 32] = e;  // == E
}

#define GMA(k) float p##k = __int_as_float(ee##k.y) * \
    bf2f(x[(long)(ee##k.x & 0x1FFFF) * 64 + d])

// spmm: one wave per row; lane = feature dim; scalar edge stream;
// 16 static register chains; cascade tails 8/4/2/1.
__global__ __launch_bounds__(256) void spmm_csr_k(
    const int* __restrict__ row_start, const int2* __restrict__ edges,
    const ushort* __restrict__ x, ushort* __restrict__ y, int N)
{
    int wid = __builtin_amdgcn_readfirstlane((int)(threadIdx.x >> 6));
    int r = blockIdx.x * 4 + wid;
    if (r >= N) return;
    int d = (int)(threadIdx.x & 63);
    int s = row_start[r];      // wave-uniform -> s_load
    int e = row_start[r + 1];
    float a0 = 0.f, a1 = 0.f, a2 = 0.f, a3 = 0.f;
    float a4 = 0.f, a5 = 0.f, a6 = 0.f, a7 = 0.f;
    float a8 = 0.f, a9 = 0.f, a10 = 0.f, a11 = 0.f;
    float a12 = 0.f, a13 = 0.f, a14 = 0.f, a15 = 0.f;
    int j = s;
    for (; j + 16 <= e; j += 16) {
        int2 ee0  = edges[j];      int2 ee1  = edges[j + 1];
        int2 ee2  = edges[j + 2];  int2 ee3  = edges[j + 3];
        int2 ee4  = edges[j + 4];  int2 ee5  = edges[j + 5];
        int2 ee6  = edges[j + 6];  int2 ee7  = edges[j + 7];
        int2 ee8  = edges[j + 8];  int2 ee9  = edges[j + 9];
        int2 ee10 = edges[j + 10]; int2 ee11 = edges[j + 11];
        int2 ee12 = edges[j + 12]; int2 ee13 = edges[j + 13];
        int2 ee14 = edges[j + 14]; int2 ee15 = edges[j + 15];
        GMA(0); GMA(1); GMA(2); GMA(3); GMA(4); GMA(5); GMA(6); GMA(7);
        GMA(8); GMA(9); GMA(10); GMA(11); GMA(12); GMA(13); GMA(14); GMA(15);
        a0 += p0;  a1 += p1;  a2 += p2;  a3 += p3;
        a4 += p4;  a5 += p5;  a6 += p6;  a7 += p7;
        a8 += p8;  a9 += p9;  a10 += p10; a11 += p11;
        a12 += p12; a13 += p13; a14 += p14; a15 += p15;
    }
    for (; j + 8 <= e; j += 8) {
        int2 ee0 = edges[j];     int2 ee1 = edges[j + 1];
        int2 ee2 = edges[j + 2]; int2 ee3 = edges[j + 3];
        int2 ee4 = edges[j + 4]; int2 ee5 = edges[j + 5];
        int2 ee6 = edges[j + 6]; int2 ee7 = edges[j + 7];
        GMA(0); GMA(1); GMA(2); GMA(3); GMA(4); GMA(5); GMA(6); GMA(7);
        a0 += p0; a1 += p1; a2 += p2; a3 += p3;
        a4 += p4; a5 += p5; a6 += p6; a7 += p7;
    }
    for (; j + 4 <= e; j += 4) {
        int2 ee0 = edges[j];     int2 ee1 = edges[j + 1];
        int2 ee2 = edges[j + 2]; int2 ee3 = edges[j + 3];
        GMA(0); GMA(1); GMA(2); GMA(3);
        a0 += p0; a1 += p1; a2 += p2; a3 += p3;
    }
    if (j + 2 <= e) {
        int2 ee0 = edges[j]; int2 ee1 = edges[j + 1];
        GMA(0); GMA(1);
        a0 += p0; a1 += p1;
        j += 2;
    }
    if (j < e) {
        int2 ee0 = edges[j];
        GMA(0);
        a0 += p0;
    }
    float sum = (((a0 + a1) + (a2 + a3)) + ((a4 + a5) + (a6 + a7)))
              + (((a8 + a9) + (a10 + a11)) + ((a12 + a13) + (a14 + a15)));
    y[(long)r * 64 + d] = f2bf(sum);
}

// out[0..2] = 0.25*emb[idx] (hop-0 term), out[3..5] = emb[idx]; float4 lanes
__global__ __launch_bounds__(256) void init_out_k(
    const float* __restrict__ emb, const int* __restrict__ n0,
    const int* __restrict__ n1, const int* __restrict__ n2,
    float* __restrict__ out, int B)
{
    int tid = blockIdx.x * blockDim.x + threadIdx.x;
    int total = 3 * B * 16;                 // float4 granularity
    if (tid >= total) return;
    int arr = tid / (B * 16);
    int rem = tid - arr * (B * 16);
    int b = rem >> 4;
    int d4 = rem & 15;
    const int* __restrict__ idx = (arr == 0) ? n0 : ((arr == 1) ? n1 : n2);
    float4 v = *(const float4*)(emb + (long)idx[b] * 64 + d4 * 4);
    float4 q = make_float4(0.25f * v.x, 0.25f * v.y, 0.25f * v.z, 0.25f * v.w);
    *(float4*)(out + (long)arr * B * 64 + (long)rem * 4) = q;
    *(float4*)(out + (long)(arr + 3) * B * 64 + (long)rem * 4) = v;
}

// pooled += 0.25 * agg_bf16[idx]
__global__ __launch_bounds__(256) void gather_add_k(
    const ushort* __restrict__ agg, const int* __restrict__ n0,
    const int* __restrict__ n1, const int* __restrict__ n2,
    float* __restrict__ out, int B)
{
    int tid = blockIdx.x * blockDim.x + threadIdx.x;
    int total = 3 * B * 16;
    if (tid >= total) return;
    int arr = tid / (B * 16);
    int rem = tid - arr * (B * 16);
    int b = rem >> 4;
    int d4 = rem & 15;
    const int* __restrict__ idx = (arr == 0) ? n0 : ((arr == 1) ? n1 : n2);
    ushort4 v = *(const ushort4*)(agg + (long)idx[b] * 64 + d4 * 4);
    float* o = out + (long)arr * B * 64 + (long)rem * 4;
    float4 cur = *(float4*)o;
    cur.x += 0.25f * bf2f(v.x); cur.y += 0.25f * bf2f(v.y);
    cur.z += 0.25f * bf2f(v.z); cur.w += 0.25f * bf2f(v.w);
    *(float4*)o = cur;
}

extern "C" void kernel_launch(void* const* d_in, const int* in_sizes, int n_in,
                              void* d_out, int out_size, void* d_ws, size_t ws_size,
                              hipStream_t stream)
{
    const float* emb  = (const float*)d_in[0];
    const int*   rows = (const int*)d_in[1];
    const int*   cols = (const int*)d_in[2];
    const float* vals = (const float*)d_in[3];
    const int*   node = (const int*)d_in[4];
    const int*   pos  = (const int*)d_in[5];
    const int*   neg  = (const int*)d_in[6];
    float* out = (float*)d_out;

    const int E = in_sizes[1];
    const int B = in_sizes[4];
    const int N = in_sizes[0] / 64;
    const size_t nd = (size_t)N * 64;
    const int chunkE = (E + NCHUNK - 1) / NCHUNK;
    const int nbucket = (N + BMASK) >> BSHIFT;     // 3125 for N=100000

    // workspace layout
    ushort* aggA        = (ushort*)d_ws;            // N*64 bf16
    ushort* aggB        = aggA + nd;                // N*64 bf16 (also emb cast)
    int2*  edges        = (int2*)(aggB + nd);       // E (bucket-grouped)
    int2*  edges2       = edges + E;                // E (row-sorted)
    int*   cnt          = (int*)(edges2 + E);       // NCHUNK * NBUCKET
    int*   totals       = cnt + (long)NCHUNK * NBUCKET;  // NBUCKET
    int*   bucket_start = totals + NBUCKET;         // NBUCKET+1
    int*   row_start    = bucket_start + NBUCKET + 1;    // nbucket*32+1
    // offs reuses edges2's storage (dead before sort_bkt writes edges2)
    int*   offs         = (int*)edges2;             // NCHUNK * NBUCKET

    const int gtotal   = 3 * B * 16;
    const int gblocks  = (gtotal + 255) / 256;
    const int cblocks  = ((int)(nd / 4) + 255) / 256;
    const int bblocks  = (nbucket + 255) / 256;     // 13
    const int dblocks  = (nbucket + 3) / 4;         // sortD: 4 buckets/block
    const int rblocks  = (N + 3) / 4;               // spmm: 4 rows/block

    init_out_k<<<gblocks, 256, 0, stream>>>(emb, node, pos, neg, out, B);
    f2bf_k<<<cblocks, 256, 0, stream>>>(emb, aggB, (int)(nd / 4));

    // ---- bucketed partition + per-bucket counting sort; no global atomics ----
    count_k<<<NCHUNK, 1024, 0, stream>>>(rows, cnt, E, chunkE);
    localscan_k<<<bblocks, 256, 0, stream>>>(cnt, offs, totals);
    scan_fused_k<<<1, 1024, 0, stream>>>(totals, bucket_start, nbucket);
    scatter3_k<<<NCHUNK, 1024, 0, stream>>>(rows, cols, vals, offs, bucket_start, edges, E, chunkE);
    sort_bkt_k<<<dblocks, 256, 0, stream>>>(bucket_start, edges, edges2, row_start, nbucket);

    // ---- 3 propagation hops, row-wave register-accumulating spmm ----
    spmm_csr_k<<<rblocks, 256, 0, stream>>>(row_start, edges2, aggB, aggA, N);
    gather_add_k<<<gblocks, 256, 0, stream>>>(aggA, node, pos, neg, out, B);

    spmm_csr_k<<<rblocks, 256, 0, stream>>>(row_start, edges2, aggA, aggB, N);
    gather_add_k<<<gblocks, 256, 0, stream>>>(aggB, node, pos, neg, out, B);

    spmm_csr_k<<<rblocks, 256, 0, stream>>>(row_start, edges2, aggB, aggA, N);
    gather_add_k<<<gblocks, 256, 0, stream>>>(aggA, node, pos, neg, out, B);
}